// Round 6
// baseline (423.193 us; speedup 1.0000x reference)
//
#include <hip/hip_runtime.h>

typedef unsigned short u16;
typedef unsigned int   u32;
typedef __bf16  bf16x8 __attribute__((ext_vector_type(8)));
typedef __bf16  bf16x2 __attribute__((ext_vector_type(2)));
typedef float   f32x4  __attribute__((ext_vector_type(4)));

static __device__ __forceinline__ float b2f(u16 v) {
    return __builtin_bit_cast(float, (u32)(((u32)v) << 16));
}
static __device__ __forceinline__ u16 f2b(float f) {  // RNE f32->bf16
    u32 u = __builtin_bit_cast(u32, f);
    return (u16)((u + 0x7FFFu + ((u >> 16) & 1u)) >> 16);
}
static __device__ __forceinline__ u32 pack2(float a, float b) {
    bf16x2 t; t[0] = (__bf16)a; t[1] = (__bf16)b;
    return __builtin_bit_cast(u32, t);
}

// ---------------------------------------------------------------------------
// LayerNorm: rows 0..4095 = x, 4096..8191 = context. 1024 f32 per row.
// ---------------------------------------------------------------------------
__global__ __launch_bounds__(256)
void ln_kernel(const float* __restrict__ x, const float* __restrict__ ctx,
               const float* __restrict__ gamma, const float* __restrict__ cgamma,
               u16* __restrict__ xn, u16* __restrict__ ctxn)
{
    const int row = blockIdx.x;
    const int tid = threadIdx.x;
    const float* src; const float* g; u16* dst;
    if (row < 4096) { src = x   + (long)row * 1024;          g = gamma;  dst = xn   + (long)row * 1024; }
    else            { src = ctx + (long)(row - 4096) * 1024; g = cgamma; dst = ctxn + (long)(row - 4096) * 1024; }
    float4 v = ((const float4*)src)[tid];
    float s = v.x + v.y + v.z + v.w;
    float q = v.x*v.x + v.y*v.y + v.z*v.z + v.w*v.w;
#pragma unroll
    for (int off = 32; off; off >>= 1) { s += __shfl_xor(s, off); q += __shfl_xor(q, off); }
    __shared__ float r1[4], r2[4];
    if ((tid & 63) == 0) { r1[tid >> 6] = s; r2[tid >> 6] = q; }
    __syncthreads();
    s = r1[0] + r1[1] + r1[2] + r1[3];
    q = r2[0] + r2[1] + r2[2] + r2[3];
    float mu   = s * (1.0f / 1024.0f);
    float var  = q * (1.0f / 1024.0f) - mu * mu;
    float rstd = rsqrtf(var + 1e-5f);
    float4 gv = ((const float4*)g)[tid];
    ushort4 o;
    o.x = f2b((v.x - mu) * rstd * gv.x);
    o.y = f2b((v.y - mu) * rstd * gv.y);
    o.z = f2b((v.z - mu) * rstd * gv.z);
    o.w = f2b((v.w - mu) * rstd * gv.w);
    ((ushort4*)dst)[tid] = o;
}

// ---------------------------------------------------------------------------
// Weight convert: W f32 [K][N] row-major -> Wt bf16 [N][K] row-major, *scale
// ---------------------------------------------------------------------------
__global__ __launch_bounds__(256)
void wconv(const float* __restrict__ W, u16* __restrict__ Wt, int N, int K, float scale)
{
    __shared__ float tile[32][33];
    const int tid = threadIdx.x;
    const int n0 = blockIdx.x * 32;
    const int k0 = blockIdx.y * 32;
    const int r  = tid >> 3;
    const int c4 = (tid & 7) * 4;
    float4 v = *(const float4*)&W[(long)(k0 + r) * N + n0 + c4];
    tile[r][c4 + 0] = v.x; tile[r][c4 + 1] = v.y; tile[r][c4 + 2] = v.z; tile[r][c4 + 3] = v.w;
    __syncthreads();
    ushort4 o;
    o.x = f2b(tile[c4 + 0][r] * scale);
    o.y = f2b(tile[c4 + 1][r] * scale);
    o.z = f2b(tile[c4 + 2][r] * scale);
    o.w = f2b(tile[c4 + 3][r] * scale);
    *(ushort4*)&Wt[(long)(n0 + r) * K + k0 + c4] = o;
}

// ---------------------------------------------------------------------------
// Wff1 convert with a/gate interleave: phys row p <- logical col
// L(p) = (p&16 ? 4096:0) + (p>>5)*16 + (p&15).
// ---------------------------------------------------------------------------
__global__ __launch_bounds__(256)
void wconv_ff1(const float* __restrict__ W, u16* __restrict__ Wt)
{
    __shared__ float tile[32][33];
    const int tid = threadIdx.x;
    const int a  = blockIdx.x;            // 0..255
    const int k0 = blockIdx.y * 32;
    const int r  = tid >> 3;
    const int c4 = (tid & 7) * 4;
    const int srccol = (c4 < 16) ? (a * 16 + c4) : (4096 + a * 16 + (c4 - 16));
    float4 v = *(const float4*)&W[(long)(k0 + r) * 8192 + srccol];
    tile[r][c4 + 0] = v.x; tile[r][c4 + 1] = v.y; tile[r][c4 + 2] = v.z; tile[r][c4 + 3] = v.w;
    __syncthreads();
    ushort4 o;
    o.x = f2b(tile[c4 + 0][r]);
    o.y = f2b(tile[c4 + 1][r]);
    o.z = f2b(tile[c4 + 2][r]);
    o.w = f2b(tile[c4 + 3][r]);
    *(ushort4*)&Wt[(long)(a * 32 + r) * 1024 + k0 + c4] = o;
}

// ---------------------------------------------------------------------------
// kext: [2][2048][64] bf16 K rows; mbias [2][2048] f32 = 0 or -1e30.
// ---------------------------------------------------------------------------
__global__ __launch_bounds__(256)
void kext_build(const float* __restrict__ kvf, const int* __restrict__ mask,
                u16* __restrict__ kext, float* __restrict__ mbias)
{
    const int gid = blockIdx.x * 256 + threadIdx.x;   // 2*2048*8 = 32768
    const int b = gid >> 14;
    const int rem = gid & 16383;
    const int j = rem >> 3;
    const int c = rem & 7;
    const float* src = &kvf[((long)b * 2048 + j) * 128 + c * 8];
    u16 ov[8];
#pragma unroll
    for (int e = 0; e < 8; ++e) ov[e] = f2b(src[e]);
    uint4 w;
    w.x = (u32)ov[0] | ((u32)ov[1] << 16);
    w.y = (u32)ov[2] | ((u32)ov[3] << 16);
    w.z = (u32)ov[4] | ((u32)ov[5] << 16);
    w.w = (u32)ov[6] | ((u32)ov[7] << 16);
    *(uint4*)&kext[((long)b * 2048 + j) * 64 + c * 8] = w;
    if (c == 0) mbias[b * 2048 + j] = mask[b * 2048 + j] ? 0.0f : -1e30f;
}

// ---------------------------------------------------------------------------
// vT [2][64][2048] bf16 <- V columns of kvf f32 [2][2048][128]
// ---------------------------------------------------------------------------
__global__ __launch_bounds__(256)
void vtrans(const float* __restrict__ kvf, u16* __restrict__ vT)
{
    const int j = blockIdx.x * 256 + threadIdx.x;
    const int d = blockIdx.y;
    const int b = blockIdx.z;
    vT[(long)b * 64 * 2048 + (long)d * 2048 + j] =
        f2b(kvf[((long)b * 2048 + j) * 128 + 64 + d]);
}

// ---------------------------------------------------------------------------
// GEMM 128x128 (m97 structure): C = A[M][K] @ Bt[N][K]^T. BK=32, 4 waves.
// EPI: 0 bf16-store, 1 f32-store, 2 f32-accumulate, 4 f32 atomic (split-K).
// ---------------------------------------------------------------------------
#define BM 128
#define BN 128
#define BK 32

template<int EPI>
__global__ __launch_bounds__(256, 2)
void gemm_bt(const u16* __restrict__ A, const u16* __restrict__ Bt,
             void* __restrict__ Cv,
             int K, int lda, int ldb, int ldc,
             long aH, long bH, long cH)
{
    __shared__ __align__(16) u16 sm[2][2][BM * BK];
    const int tid  = threadIdx.x;
    const int wave = tid >> 6;
    const int lane = tid & 63;
    const int tn = blockIdx.x * BN;
    const int tm = blockIdx.y * BM;
    const int z  = blockIdx.z;
    A  += (long)z * aH;
    Bt += (long)z * bH;

    const int arow0 = (tid >> 2);
    const int arow1 = 64 + (tid >> 2);
    const int acs0  = (tid & 3) ^ ((arow0 >> 1) & 3);
    const int acs1  = (tid & 3) ^ ((arow1 >> 1) & 3);
    const int nt = K / BK;

#define STAGE(buf, k0)                                                                              \
    do {                                                                                            \
        __builtin_amdgcn_global_load_lds(                                                           \
            (const __attribute__((address_space(1))) void*)(A + (long)(tm + arow0) * lda + (k0) + acs0 * 8),   \
            (__attribute__((address_space(3))) void*)(&sm[buf][0][(wave * 64) * 8]), 16, 0, 0);     \
        __builtin_amdgcn_global_load_lds(                                                           \
            (const __attribute__((address_space(1))) void*)(A + (long)(tm + arow1) * lda + (k0) + acs1 * 8),   \
            (__attribute__((address_space(3))) void*)(&sm[buf][0][(256 + wave * 64) * 8]), 16, 0, 0); \
        __builtin_amdgcn_global_load_lds(                                                           \
            (const __attribute__((address_space(1))) void*)(Bt + (long)(tn + arow0) * ldb + (k0) + acs0 * 8),  \
            (__attribute__((address_space(3))) void*)(&sm[buf][1][(wave * 64) * 8]), 16, 0, 0);     \
        __builtin_amdgcn_global_load_lds(                                                           \
            (const __attribute__((address_space(1))) void*)(Bt + (long)(tn + arow1) * ldb + (k0) + acs1 * 8),  \
            (__attribute__((address_space(3))) void*)(&sm[buf][1][(256 + wave * 64) * 8]), 16, 0, 0); \
    } while (0)

    STAGE(0, 0);

    f32x4 acc[4][4] = {};
    const int wr   = (wave >> 1) * 64;
    const int wc   = (wave & 1) * 64;
    const int frow = lane & 15;
    const int fk   = lane >> 4;

    for (int t = 0; t < nt; ++t) {
        __syncthreads();
        if (t + 1 < nt) STAGE((t + 1) & 1, (t + 1) * BK);
        const int cur = t & 1;
        bf16x8 af[4], bf[4];
#pragma unroll
        for (int m = 0; m < 4; ++m) {
            int row = wr + m * 16 + frow;
            af[m] = *(const bf16x8*)&sm[cur][0][row * BK + ((fk ^ ((row >> 1) & 3)) * 8)];
        }
#pragma unroll
        for (int n = 0; n < 4; ++n) {
            int row = wc + n * 16 + frow;
            bf[n] = *(const bf16x8*)&sm[cur][1][row * BK + ((fk ^ ((row >> 1) & 3)) * 8)];
        }
#pragma unroll
        for (int m = 0; m < 4; ++m)
#pragma unroll
            for (int n = 0; n < 4; ++n)
                acc[m][n] = __builtin_amdgcn_mfma_f32_16x16x32_bf16(af[m], bf[n], acc[m][n], 0, 0, 0);
    }
#undef STAGE

    const long coff = (long)z * cH;
#pragma unroll
    for (int m = 0; m < 4; ++m) {
        const int row0 = tm + wr + m * 16 + fk * 4;
#pragma unroll
        for (int n = 0; n < 4; ++n) {
            const int col = tn + wc + n * 16 + frow;
#pragma unroll
            for (int r = 0; r < 4; ++r) {
                const long off = coff + (long)(row0 + r) * ldc + col;
                const float v = acc[m][n][r];
                if constexpr (EPI == 0)      ((u16*)Cv)[off] = f2b(v);
                else if constexpr (EPI == 1) ((float*)Cv)[off] = v;
                else if constexpr (EPI == 2) ((float*)Cv)[off] += v;
                else                         atomicAdd(&((float*)Cv)[off], v);
            }
        }
    }
}

// ---------------------------------------------------------------------------
// GEMM 256x256, BK=64, 512 thr (8 waves 2Mx4N), 8-phase schedule with
// REGISTER-PERSISTENT fragments: each A/B half-tile fragment set is
// ds_read exactly ONCE per K-tile (24 b128/wave/K-tile, was 48):
//   P0: read A0,B0 ; stage A1(t+1)->nxt ; MFMA A0B0
//   P1: read B1    ; stage B1(t+1)->nxt ; MFMA A0B1
//   P2: read A1    ; stage B0(t+2)->cur ; MFMA A1B1   (B0 region dead @P0)
//   P3: (no reads) ; stage A0(t+2)->cur ; MFMA A1B0   (A0 region dead @P0)
// Counted s_waitcnt vmcnt(4) once per K-tile boundary. XOR chunk swizzle
// with pre-swizzled global source. EPI 3 = fused swiglu bf16 (FF1, paired
// interleaved cols); EPI 4 = f32 atomicAdd (FF2 split-K).
// ---------------------------------------------------------------------------
template<int EPI>
__global__ __launch_bounds__(512, 2)
void gemm256(const u16* __restrict__ A, const u16* __restrict__ Bt,
             void* __restrict__ Cv, int K, int lda, int ldb, int ldc,
             long aH, long bH)
{
    __shared__ __align__(16) u16 As[2][256 * 64];
    __shared__ __align__(16) u16 Bs[2][256 * 64];
    const int tid  = threadIdx.x;
    const int wave = tid >> 6, lane = tid & 63;
    const int wm = wave >> 2, wn = wave & 3;
    const int frow = lane & 15, fk = lane >> 4;
    const int tn = blockIdx.x * 256;
    const int tm = blockIdx.y * 256;
    const int z  = blockIdx.z;
    A  += (long)z * aH;
    Bt += (long)z * bH;
    const int nt = K >> 6;

    const int lrow  = lane >> 3;
    const int csrc8 = ((lane & 7) ^ lrow) * 8;
    int rbA0[2], rbA1[2], rbB0[2], rbB1[2];
#pragma unroll
    for (int g = 0; g < 2; ++g) {
        const int c = g * 8 + wave;
        const int a0 = ((c >> 3) * 128) + ((c & 7) * 8);
        rbA0[g] = a0; rbA1[g] = a0 + 64;
        const int b0 = ((c >> 2) * 64) + ((c & 3) * 8);
        rbB0[g] = b0; rbB1[g] = b0 + 32;
    }

#define STG(LDS, buf, src, toff, ld, kt, rb)                                                        \
    __builtin_amdgcn_global_load_lds(                                                               \
        (const __attribute__((address_space(1))) void*)((src) + (long)((toff) + (rb) + lrow) * (ld) + ((kt) << 6) + csrc8), \
        (__attribute__((address_space(3))) void*)(&LDS[buf][(rb) * 64]), 16, 0, 0)

#define STAGE_A0(buf, kt) do { STG(As, buf, A,  tm, lda, kt, rbA0[0]); STG(As, buf, A,  tm, lda, kt, rbA0[1]); } while (0)
#define STAGE_A1(buf, kt) do { STG(As, buf, A,  tm, lda, kt, rbA1[0]); STG(As, buf, A,  tm, lda, kt, rbA1[1]); } while (0)
#define STAGE_B0(buf, kt) do { STG(Bs, buf, Bt, tn, ldb, kt, rbB0[0]); STG(Bs, buf, Bt, tn, ldb, kt, rbB0[1]); } while (0)
#define STAGE_B1(buf, kt) do { STG(Bs, buf, Bt, tn, ldb, kt, rbB1[0]); STG(Bs, buf, Bt, tn, ldb, kt, rbB1[1]); } while (0)

#define DSREAD_A(dst, half)                                                                         \
    do { _Pragma("unroll") for (int i = 0; i < 4; ++i) {                                            \
        const int row = wm * 128 + (half) * 64 + i * 16 + frow;                                     \
        _Pragma("unroll") for (int kk = 0; kk < 2; ++kk)                                            \
            dst[i][kk] = *(const bf16x8*)&As[cur][row * 64 + (((kk * 4 + fk) ^ (row & 7)) * 8)];    \
    } } while (0)
#define DSREAD_B(dst, half)                                                                         \
    do { _Pragma("unroll") for (int j = 0; j < 2; ++j) {                                            \
        const int row = wn * 64 + (half) * 32 + j * 16 + frow;                                      \
        _Pragma("unroll") for (int kk = 0; kk < 2; ++kk)                                            \
            dst[j][kk] = *(const bf16x8*)&Bs[cur][row * 64 + (((kk * 4 + fk) ^ (row & 7)) * 8)];    \
    } } while (0)
#define MFMA_Q(afr, bfr, mh, nh)                                                                    \
    do { __builtin_amdgcn_s_setprio(1);                                                             \
    _Pragma("unroll") for (int kk = 0; kk < 2; ++kk)                                                \
        _Pragma("unroll") for (int i = 0; i < 4; ++i)                                               \
            _Pragma("unroll") for (int j = 0; j < 2; ++j)                                           \
                acc[(mh) * 4 + i][(nh) * 2 + j] = __builtin_amdgcn_mfma_f32_16x16x32_bf16(          \
                    afr[i][kk], bfr[j][kk], acc[(mh) * 4 + i][(nh) * 2 + j], 0, 0, 0);              \
    __builtin_amdgcn_s_setprio(0); } while (0)
#define LGKM0 do { asm volatile("s_waitcnt lgkmcnt(0)" ::: "memory"); __builtin_amdgcn_sched_barrier(0); } while (0)
#define SB    __builtin_amdgcn_sched_barrier(0)
#define BAR   __builtin_amdgcn_s_barrier()

    // prologue: tile0 all 4 regions + tile1 B0/A0; wait tile0's 8 landed.
    STAGE_B0(0, 0); STAGE_A0(0, 0); STAGE_A1(0, 0); STAGE_B1(0, 0);
    if (nt > 1) {
        STAGE_B0(1, 1); STAGE_A0(1, 1);
        asm volatile("s_waitcnt vmcnt(4)" ::: "memory");
    } else {
        asm volatile("s_waitcnt vmcnt(0)" ::: "memory");
    }
    SB;
    BAR;

    f32x4 acc[8][4] = {};
    bf16x8 a0f[4][2], a1f[4][2], b0f[2][2], b1f[2][2];

    for (int t = 0; t < nt; ++t) {
        const int cur = t & 1, nxt = cur ^ 1;
        // P0: A0,B0 -> MFMA A0B0
        DSREAD_A(a0f, 0); DSREAD_B(b0f, 0);
        if (t + 1 < nt) STAGE_A1(nxt, t + 1);
        BAR; LGKM0;
        MFMA_Q(a0f, b0f, 0, 0);
        SB; BAR;
        // P1: B1 -> MFMA A0B1
        DSREAD_B(b1f, 1);
        if (t + 1 < nt) STAGE_B1(nxt, t + 1);
        BAR; LGKM0;
        MFMA_Q(a0f, b1f, 0, 1);
        SB; BAR;
        // P2: A1 -> MFMA A1B1
        DSREAD_A(a1f, 1);
        if (t + 2 < nt) STAGE_B0(cur, t + 2);
        BAR; LGKM0;
        MFMA_Q(a1f, b1f, 1, 1);
        SB; BAR;
        // P3: no reads -> MFMA A1B0
        if (t + 2 < nt) STAGE_A0(cur, t + 2);
        BAR;
        MFMA_Q(a1f, b0f, 1, 0);
        SB;
        if (t + 1 < nt) {
            if (t + 2 < nt) asm volatile("s_waitcnt vmcnt(4)" ::: "memory");
            else            asm volatile("s_waitcnt vmcnt(0)" ::: "memory");
            SB;
            BAR;
        }
    }
#undef BAR
#undef SB
#undef LGKM0
#undef MFMA_Q
#undef DSREAD_A
#undef DSREAD_B
#undef STAGE_A0
#undef STAGE_A1
#undef STAGE_B0
#undef STAGE_B1
#undef STG

    if constexpr (EPI == 3) {
        // fused swiglu: B phys rows nf even = a, nf odd = gate;
        // silu col = (tn>>1) + (wn*2 + nf/2)*16 + frow.
        u16* C = (u16*)Cv;
#pragma unroll
        for (int mf = 0; mf < 8; ++mf) {
            const int gr = tm + wm * 128 + mf * 16 + fk * 4;
#pragma unroll
            for (int np = 0; np < 4; np += 2) {
                const int scol = (tn >> 1) + (wn * 2 + (np >> 1)) * 16 + frow;
                const f32x4 av = acc[mf][np];
                const f32x4 gv = acc[mf][np + 1];
#pragma unroll
                for (int r = 0; r < 4; ++r) {
                    const float g = gv[r];
                    const float o = av[r] * g / (1.0f + __expf(-g));
                    C[(long)(gr + r) * ldc + scol] = f2b(o);
                }
            }
        }
    } else {
        float* C = (float*)Cv;
#pragma unroll
        for (int mf = 0; mf < 8; ++mf) {
            const int gr = tm + wm * 128 + mf * 16 + fk * 4;
#pragma unroll
            for (int nf = 0; nf < 4; ++nf) {
                const int col = tn + wn * 64 + nf * 16 + frow;
#pragma unroll
                for (int r = 0; r < 4; ++r)
                    atomicAdd(&C[(long)(gr + r) * ldc + col], acc[mf][nf][r]);
            }
        }
    }
}

// ---------------------------------------------------------------------------
// Flash attention. Grid (32 qtiles, 16 heads, 2 batches), 256 thr = 4 waves;
// QBLK=64 (16 q/wave), JBLK=64. K/V staged via global_load_lds into double-
// buffered LDS shared by all waves. Mask = f32 bias. 40KB LDS -> 4 blocks/CU.
// ---------------------------------------------------------------------------
__global__ __launch_bounds__(256, 4)
void flash_attn(const u16* __restrict__ qb, const u16* __restrict__ kext,
                const u16* __restrict__ vT, const float* __restrict__ mbias,
                u16* __restrict__ aout)
{
    __shared__ __align__(16) u16 Ksm[2][4096];   // [64 j][64 d], chunk-swizzled
    __shared__ __align__(16) u16 Vsm[2][4096];   // [64 d][64 j], chunk-swizzled
    __shared__ __align__(16) u16 Psm[4][1024];   // per-wave [16 q][64 j], swz
    const int tid  = threadIdx.x;
    const int wave = tid >> 6, lane = tid & 63;
    const int frow = lane & 15, fk = lane >> 4;
    const int b = blockIdx.z, h = blockIdx.y;
    const int q0 = blockIdx.x * 64;

    const u16* kx = kext + (long)b * 2048 * 64;
    const u16* vb = vT   + (long)b * 64 * 2048;
    const float* mbb = mbias + b * 2048;

    const u16* qbase = qb + ((long)(b * 2048 + q0 + wave * 16 + frow)) * 1024 + h * 64;
    bf16x8 bq[2];
#pragma unroll
    for (int kk = 0; kk < 2; ++kk)
        bq[kk] = *(const bf16x8*)&qbase[kk * 32 + fk * 8];

#define FSTAGE(buf, j0s)                                                                             \
    do {                                                                                             \
        _Pragma("unroll")                                                                            \
        for (int i = 0; i < 2; ++i) {                                                                \
            const int slot = i * 256 + tid;                                                          \
            const int row  = slot >> 3;                                                              \
            const int csrc = (slot & 7) ^ (row & 7);                                                 \
            __builtin_amdgcn_global_load_lds(                                                        \
                (const __attribute__((address_space(1))) void*)(kx + (long)((j0s) + row) * 64 + csrc * 8), \
                (__attribute__((address_space(3))) void*)(&Ksm[buf][(i * 256 + wave * 64) * 8]), 16, 0, 0); \
            __builtin_amdgcn_global_load_lds(                                                        \
                (const __attribute__((address_space(1))) void*)(vb + (long)row * 2048 + (j0s) + csrc * 8),  \
                (__attribute__((address_space(3))) void*)(&Vsm[buf][(i * 256 + wave * 64) * 8]), 16, 0, 0); \
        }                                                                                            \
    } while (0)

    FSTAGE(0, 0);

    f32x4 oacc[4] = {};
    float mrun = -1e30f, lrun = 0.0f;
    u16* pw = &Psm[wave][0];

    for (int it = 0; it < 32; ++it) {
        const int j0 = it * 64;
        __syncthreads();
        float4 mb[4];
#pragma unroll
        for (int m = 0; m < 4; ++m)
            mb[m] = *(const float4*)&mbb[j0 + m * 16 + fk * 4];
        if (it + 1 < 32) FSTAGE((it + 1) & 1, (it + 1) * 64);
        const int cur = it & 1;

        f32x4 st[4] = {};
        __builtin_amdgcn_s_setprio(1);
#pragma unroll
        for (int kk = 0; kk < 2; ++kk) {
            bf16x8 ka[4];
#pragma unroll
            for (int m = 0; m < 4; ++m) {
                const int row = m * 16 + frow;
                ka[m] = *(const bf16x8*)&Ksm[cur][row * 64 + (((kk * 4 + fk) ^ (row & 7)) * 8)];
            }
#pragma unroll
            for (int m = 0; m < 4; ++m)
                st[m] = __builtin_amdgcn_mfma_f32_16x16x32_bf16(ka[m], bq[kk], st[m], 0, 0, 0);
        }
        __builtin_amdgcn_s_setprio(0);

        float sb[4][4];
#pragma unroll
        for (int m = 0; m < 4; ++m)
#pragma unroll
            for (int r = 0; r < 4; ++r) sb[m][r] = st[m][r] + (&mb[m].x)[r];
        float pm = fmaxf(
            fmaxf(fmaxf(sb[0][0], sb[0][1]), fmaxf(sb[0][2], sb[0][3])),
            fmaxf(fmaxf(sb[1][0], sb[1][1]), fmaxf(sb[1][2], sb[1][3])));
        pm = fmaxf(pm, fmaxf(
            fmaxf(fmaxf(sb[2][0], sb[2][1]), fmaxf(sb[2][2], sb[2][3])),
            fmaxf(fmaxf(sb[3][0], sb[3][1]), fmaxf(sb[3][2], sb[3][3]))));
        pm = fmaxf(pm, __shfl_xor(pm, 16));
        pm = fmaxf(pm, __shfl_xor(pm, 32));
        const float nm = fmaxf(mrun, pm);
        const float alpha = __expf(mrun - nm);
        mrun = nm;

        float rs = 0.0f;
#pragma unroll
        for (int m = 0; m < 4; ++m) {
            const float p0 = __expf(sb[m][0] - nm);
            const float p1 = __expf(sb[m][1] - nm);
            const float p2 = __expf(sb[m][2] - nm);
            const float p3 = __expf(sb[m][3] - nm);
            rs += (p0 + p1) + (p2 + p3);
            const int chunk = (m * 2 + (fk >> 1)) ^ (frow & 7);
            uint2 w; w.x = pack2(p0, p1); w.y = pack2(p2, p3);
            *(uint2*)&pw[frow * 64 + chunk * 8 + (fk & 1) * 4] = w;
        }
        rs += __shfl_xor(rs, 16);
        rs += __shfl_xor(rs, 32);
        lrun = lrun * alpha + rs;
#pragma unroll
        for (int mo = 0; mo < 4; ++mo)
#pragma unroll
            for (int r = 0; r < 4; ++r) oacc[mo][r] *= alpha;

        __builtin_amdgcn_s_setprio(1);
#pragma unroll
        for (int kkv = 0; kkv < 2; ++kkv) {
            bf16x8 va[4];
#pragma unroll
            for (int mo = 0; mo < 4; ++mo) {
                const int row = mo * 16 + frow;
                va[mo] = *(const bf16x8*)&Vsm[cur][row * 64 + (((kkv * 4 + fk) ^ (row & 7)) * 8)];
            }
            const bf16x8 pb = *(const bf16x8*)&pw[frow * 64 + (((kkv * 4 + fk) ^ (frow & 7)) * 8)];
#pragma unroll
            for (int mo = 0; mo < 4; ++mo)
                oacc[mo] = __builtin_amdgcn_mfma_f32_16x16x32_bf16(va[mo], pb, oacc[mo], 0, 0, 0);
        }
        __builtin_amdgcn_s_setprio(0);
    }
#undef FSTAGE

    const float inv = 1.0f / lrun;
    const long row = (long)b * 2048 + q0 + wave * 16 + frow;
#pragma unroll
    for (int mo = 0; mo < 4; ++mo) {
        uint2 w;
        w.x = pack2(oacc[mo][0] * inv, oacc[mo][1] * inv);
        w.y = pack2(oacc[mo][2] * inv, oacc[mo][3] * inv);
        *(uint2*)&aout[row * 1024 + h * 64 + mo * 16 + fk * 4] = w;
    }
}

// ---------------------------------------------------------------------------
extern "C" void kernel_launch(void* const* d_in, const int* in_sizes, int n_in,
                              void* d_out, int out_size, void* d_ws, size_t ws_size,
                              hipStream_t stream)
{
    const float* x      = (const float*)d_in[0];
    const float* ctx    = (const float*)d_in[1];
    const int*   mask   = (const int*)d_in[2];
    const float* gamma  = (const float*)d_in[3];
    const float* cgamma = (const float*)d_in[4];
    const float* Wq     = (const float*)d_in[5];
    const float* Wkv    = (const float*)d_in[6];
    const float* Wout   = (const float*)d_in[7];
    const float* Wff1   = (const float*)d_in[8];
    const float* Wff2   = (const float*)d_in[9];
    float* out = (float*)d_out;

    char* w = (char*)d_ws;
    auto carveB = [&](long bytes) { char* p = w; w += ((bytes + 255) / 256) * 256; return p; };
    u16*   xn     = (u16*)  carveB(4096L * 1024 * 2);
    u16*   ctxn   = (u16*)  carveB(4096L * 1024 * 2);
    u16*   WqT    = (u16*)  carveB(1024L * 1024 * 2);
    u16*   WkvT   = (u16*)  carveB(128L * 1024 * 2);
    u16*   WoutT  = (u16*)  carveB(1024L * 1024 * 2);
    u16*   Wff1Tp = (u16*)  carveB(8192L * 1024 * 2);
    u16*   Wff2T  = (u16*)  carveB(1024L * 4096 * 2);
    u16*   q      = (u16*)  carveB(4096L * 1024 * 2);
    float* kvf    = (float*)carveB(2L * 2048 * 128 * 4);
    u16*   kext   = (u16*)  carveB(2L * 2048 * 64 * 2);
    float* mbias  = (float*)carveB(2L * 2048 * 4);
    u16*   vT     = (u16*)  carveB(2L * 64 * 2048 * 2);
    u16*   aout   = (u16*)  carveB(4096L * 1024 * 2);
    u16*   gbuf   = (u16*)  carveB(4096L * 4096 * 2);

    dim3 B(256);

    ln_kernel<<<dim3(8192), B, 0, stream>>>(x, ctx, gamma, cgamma, xn, ctxn);
    wconv<<<dim3(32, 32),  B, 0, stream>>>(Wq,   WqT,   1024, 1024, 0.125f);  // q scale folded
    wconv<<<dim3(4, 32),   B, 0, stream>>>(Wkv,  WkvT,  128,  1024, 1.0f);
    wconv<<<dim3(32, 32),  B, 0, stream>>>(Wout, WoutT, 1024, 1024, 1.0f);
    wconv_ff1<<<dim3(256, 32), B, 0, stream>>>(Wff1, Wff1Tp);
    wconv<<<dim3(32, 128), B, 0, stream>>>(Wff2, Wff2T, 1024, 4096, 1.0f);

    // q = xn @ WqT^T : M=4096 N=1024 K=1024
    gemm_bt<0><<<dim3(8, 32, 1), B, 0, stream>>>(xn, WqT, q, 1024, 1024, 1024, 1024, 0, 0, 0);
    // kvf = ctxn @ WkvT^T (f32, split-K x4 atomic): M=4096 N=128 K=1024
    hipMemsetAsync(kvf, 0, 2L * 2048 * 128 * 4, stream);
    gemm_bt<4><<<dim3(1, 32, 4), B, 0, stream>>>(ctxn, WkvT, kvf, 256, 1024, 1024, 128, 256, 256, 0);
    kext_build<<<dim3(128), B, 0, stream>>>(kvf, mask, kext, mbias);
    vtrans<<<dim3(8, 64, 2), B, 0, stream>>>(kvf, vT);

    // fused attention -> aout [b][q][h*64+d]
    flash_attn<<<dim3(32, 16, 2), B, 0, stream>>>(q, kext, vT, mbias, aout);

    // out = aout @ WoutT^T (f32 write)
    gemm_bt<1><<<dim3(8, 32, 1), B, 0, stream>>>(aout, WoutT, out, 1024, 1024, 1024, 1024, 0, 0, 0);
    // gbuf = swiglu(xn @ Wff1Tp^T) : 8-phase 256^2 GEMM, N=8192
    gemm256<3><<<dim3(32, 16, 1), dim3(512), 0, stream>>>(xn, Wff1Tp, gbuf, 1024, 1024, 1024, 4096, 0, 0);
    // out += gbuf @ Wff2T^T : 256^2 8-phase, split-K x4 (f32 atomic), 256 blocks
    gemm256<4><<<dim3(4, 16, 4), dim3(512), 0, stream>>>(gbuf, Wff2T, out, 1024, 4096, 4096, 1024, 1024, 1024);
}

// Round 9
// 410.797 us; speedup vs baseline: 1.0302x; 1.0302x over previous
//
#include <hip/hip_runtime.h>

typedef unsigned short u16;
typedef unsigned int   u32;
typedef __bf16  bf16x8 __attribute__((ext_vector_type(8)));
typedef __bf16  bf16x2 __attribute__((ext_vector_type(2)));
typedef float   f32x4  __attribute__((ext_vector_type(4)));

static __device__ __forceinline__ float b2f(u16 v) {
    return __builtin_bit_cast(float, (u32)(((u32)v) << 16));
}
static __device__ __forceinline__ u16 f2b(float f) {  // RNE f32->bf16
    u32 u = __builtin_bit_cast(u32, f);
    return (u16)((u + 0x7FFFu + ((u >> 16) & 1u)) >> 16);
}
static __device__ __forceinline__ u32 pack2(float a, float b) {
    bf16x2 t; t[0] = (__bf16)a; t[1] = (__bf16)b;
    return __builtin_bit_cast(u32, t);
}

// ---------------------------------------------------------------------------
// LayerNorm: rows 0..4095 = x, 4096..8191 = context. 1024 f32 per row.
// ---------------------------------------------------------------------------
__global__ __launch_bounds__(256)
void ln_kernel(const float* __restrict__ x, const float* __restrict__ ctx,
               const float* __restrict__ gamma, const float* __restrict__ cgamma,
               u16* __restrict__ xn, u16* __restrict__ ctxn)
{
    const int row = blockIdx.x;
    const int tid = threadIdx.x;
    const float* src; const float* g; u16* dst;
    if (row < 4096) { src = x   + (long)row * 1024;          g = gamma;  dst = xn   + (long)row * 1024; }
    else            { src = ctx + (long)(row - 4096) * 1024; g = cgamma; dst = ctxn + (long)(row - 4096) * 1024; }
    float4 v = ((const float4*)src)[tid];
    float s = v.x + v.y + v.z + v.w;
    float q = v.x*v.x + v.y*v.y + v.z*v.z + v.w*v.w;
#pragma unroll
    for (int off = 32; off; off >>= 1) { s += __shfl_xor(s, off); q += __shfl_xor(q, off); }
    __shared__ float r1[4], r2[4];
    if ((tid & 63) == 0) { r1[tid >> 6] = s; r2[tid >> 6] = q; }
    __syncthreads();
    s = r1[0] + r1[1] + r1[2] + r1[3];
    q = r2[0] + r2[1] + r2[2] + r2[3];
    float mu   = s * (1.0f / 1024.0f);
    float var  = q * (1.0f / 1024.0f) - mu * mu;
    float rstd = rsqrtf(var + 1e-5f);
    float4 gv = ((const float4*)g)[tid];
    ushort4 o;
    o.x = f2b((v.x - mu) * rstd * gv.x);
    o.y = f2b((v.y - mu) * rstd * gv.y);
    o.z = f2b((v.z - mu) * rstd * gv.z);
    o.w = f2b((v.w - mu) * rstd * gv.w);
    ((ushort4*)dst)[tid] = o;
}

// ---------------------------------------------------------------------------
// Weight convert: W f32 [K][N] row-major -> Wt bf16 [N][ldout], cols koff..
// koff+K-1, *scale. Lets multiple weights stack into one B^T buffer.
// ---------------------------------------------------------------------------
__global__ __launch_bounds__(256)
void wconv(const float* __restrict__ W, u16* __restrict__ Wt, int N, int K,
           int ldout, int koff, float scale)
{
    __shared__ float tile[32][33];
    const int tid = threadIdx.x;
    const int n0 = blockIdx.x * 32;
    const int k0 = blockIdx.y * 32;
    const int r  = tid >> 3;
    const int c4 = (tid & 7) * 4;
    float4 v = *(const float4*)&W[(long)(k0 + r) * N + n0 + c4];
    tile[r][c4 + 0] = v.x; tile[r][c4 + 1] = v.y; tile[r][c4 + 2] = v.z; tile[r][c4 + 3] = v.w;
    __syncthreads();
    ushort4 o;
    o.x = f2b(tile[c4 + 0][r] * scale);
    o.y = f2b(tile[c4 + 1][r] * scale);
    o.z = f2b(tile[c4 + 2][r] * scale);
    o.w = f2b(tile[c4 + 3][r] * scale);
    *(ushort4*)&Wt[(long)(n0 + r) * ldout + koff + k0 + c4] = o;
}

// ---------------------------------------------------------------------------
// Wff1 convert with a/gate interleave: phys row p <- logical col
// L(p) = (p&16 ? 4096:0) + (p>>5)*16 + (p&15).
// ---------------------------------------------------------------------------
__global__ __launch_bounds__(256)
void wconv_ff1(const float* __restrict__ W, u16* __restrict__ Wt)
{
    __shared__ float tile[32][33];
    const int tid = threadIdx.x;
    const int a  = blockIdx.x;            // 0..255
    const int k0 = blockIdx.y * 32;
    const int r  = tid >> 3;
    const int c4 = (tid & 7) * 4;
    const int srccol = (c4 < 16) ? (a * 16 + c4) : (4096 + a * 16 + (c4 - 16));
    float4 v = *(const float4*)&W[(long)(k0 + r) * 8192 + srccol];
    tile[r][c4 + 0] = v.x; tile[r][c4 + 1] = v.y; tile[r][c4 + 2] = v.z; tile[r][c4 + 3] = v.w;
    __syncthreads();
    ushort4 o;
    o.x = f2b(tile[c4 + 0][r]);
    o.y = f2b(tile[c4 + 1][r]);
    o.z = f2b(tile[c4 + 2][r]);
    o.w = f2b(tile[c4 + 3][r]);
    *(ushort4*)&Wt[(long)(a * 32 + r) * 1024 + k0 + c4] = o;
}

// ---------------------------------------------------------------------------
// kext: [2][2048][64] bf16 K rows; mbias [2][2048] f32 = 0 or -1e30.
// ---------------------------------------------------------------------------
__global__ __launch_bounds__(256)
void kext_build(const float* __restrict__ kvf, const int* __restrict__ mask,
                u16* __restrict__ kext, float* __restrict__ mbias)
{
    const int gid = blockIdx.x * 256 + threadIdx.x;   // 2*2048*8 = 32768
    const int b = gid >> 14;
    const int rem = gid & 16383;
    const int j = rem >> 3;
    const int c = rem & 7;
    const float* src = &kvf[((long)b * 2048 + j) * 128 + c * 8];
    u16 ov[8];
#pragma unroll
    for (int e = 0; e < 8; ++e) ov[e] = f2b(src[e]);
    uint4 w;
    w.x = (u32)ov[0] | ((u32)ov[1] << 16);
    w.y = (u32)ov[2] | ((u32)ov[3] << 16);
    w.z = (u32)ov[4] | ((u32)ov[5] << 16);
    w.w = (u32)ov[6] | ((u32)ov[7] << 16);
    *(uint4*)&kext[((long)b * 2048 + j) * 64 + c * 8] = w;
    if (c == 0) mbias[b * 2048 + j] = mask[b * 2048 + j] ? 0.0f : -1e30f;
}

// ---------------------------------------------------------------------------
// vT [2][64][2048] bf16 <- V columns of kvf f32 [2][2048][128]
// ---------------------------------------------------------------------------
__global__ __launch_bounds__(256)
void vtrans(const float* __restrict__ kvf, u16* __restrict__ vT)
{
    const int j = blockIdx.x * 256 + threadIdx.x;
    const int d = blockIdx.y;
    const int b = blockIdx.z;
    vT[(long)b * 64 * 2048 + (long)d * 2048 + j] =
        f2b(kvf[((long)b * 2048 + j) * 128 + 64 + d]);
}

// ---------------------------------------------------------------------------
// GEMM 128x128 (m97 structure): C = A[M][K] @ Bt[N][K]^T. BK=32, 4 waves.
// EPI: 0 bf16-store, 1 f32-store, 2 f32-accumulate, 4 f32 atomic (split-K).
// ---------------------------------------------------------------------------
#define BM 128
#define BN 128
#define BK 32

template<int EPI>
__global__ __launch_bounds__(256, 2)
void gemm_bt(const u16* __restrict__ A, const u16* __restrict__ Bt,
             void* __restrict__ Cv,
             int K, int lda, int ldb, int ldc,
             long aH, long bH, long cH)
{
    __shared__ __align__(16) u16 sm[2][2][BM * BK];
    const int tid  = threadIdx.x;
    const int wave = tid >> 6;
    const int lane = tid & 63;
    const int tn = blockIdx.x * BN;
    const int tm = blockIdx.y * BM;
    const int z  = blockIdx.z;
    A  += (long)z * aH;
    Bt += (long)z * bH;

    const int arow0 = (tid >> 2);
    const int arow1 = 64 + (tid >> 2);
    const int acs0  = (tid & 3) ^ ((arow0 >> 1) & 3);
    const int acs1  = (tid & 3) ^ ((arow1 >> 1) & 3);
    const int nt = K / BK;

#define STAGE(buf, k0)                                                                              \
    do {                                                                                            \
        __builtin_amdgcn_global_load_lds(                                                           \
            (const __attribute__((address_space(1))) void*)(A + (long)(tm + arow0) * lda + (k0) + acs0 * 8),   \
            (__attribute__((address_space(3))) void*)(&sm[buf][0][(wave * 64) * 8]), 16, 0, 0);     \
        __builtin_amdgcn_global_load_lds(                                                           \
            (const __attribute__((address_space(1))) void*)(A + (long)(tm + arow1) * lda + (k0) + acs1 * 8),   \
            (__attribute__((address_space(3))) void*)(&sm[buf][0][(256 + wave * 64) * 8]), 16, 0, 0); \
        __builtin_amdgcn_global_load_lds(                                                           \
            (const __attribute__((address_space(1))) void*)(Bt + (long)(tn + arow0) * ldb + (k0) + acs0 * 8),  \
            (__attribute__((address_space(3))) void*)(&sm[buf][1][(wave * 64) * 8]), 16, 0, 0);     \
        __builtin_amdgcn_global_load_lds(                                                           \
            (const __attribute__((address_space(1))) void*)(Bt + (long)(tn + arow1) * ldb + (k0) + acs1 * 8),  \
            (__attribute__((address_space(3))) void*)(&sm[buf][1][(256 + wave * 64) * 8]), 16, 0, 0); \
    } while (0)

    STAGE(0, 0);

    f32x4 acc[4][4] = {};
    const int wr   = (wave >> 1) * 64;
    const int wc   = (wave & 1) * 64;
    const int frow = lane & 15;
    const int fk   = lane >> 4;

    for (int t = 0; t < nt; ++t) {
        __syncthreads();
        if (t + 1 < nt) STAGE((t + 1) & 1, (t + 1) * BK);
        const int cur = t & 1;
        bf16x8 af[4], bf[4];
#pragma unroll
        for (int m = 0; m < 4; ++m) {
            int row = wr + m * 16 + frow;
            af[m] = *(const bf16x8*)&sm[cur][0][row * BK + ((fk ^ ((row >> 1) & 3)) * 8)];
        }
#pragma unroll
        for (int n = 0; n < 4; ++n) {
            int row = wc + n * 16 + frow;
            bf[n] = *(const bf16x8*)&sm[cur][1][row * BK + ((fk ^ ((row >> 1) & 3)) * 8)];
        }
#pragma unroll
        for (int m = 0; m < 4; ++m)
#pragma unroll
            for (int n = 0; n < 4; ++n)
                acc[m][n] = __builtin_amdgcn_mfma_f32_16x16x32_bf16(af[m], bf[n], acc[m][n], 0, 0, 0);
    }
#undef STAGE

    const long coff = (long)z * cH;
#pragma unroll
    for (int m = 0; m < 4; ++m) {
        const int row0 = tm + wr + m * 16 + fk * 4;
#pragma unroll
        for (int n = 0; n < 4; ++n) {
            const int col = tn + wc + n * 16 + frow;
#pragma unroll
            for (int r = 0; r < 4; ++r) {
                const long off = coff + (long)(row0 + r) * ldc + col;
                const float v = acc[m][n][r];
                if constexpr (EPI == 0)      ((u16*)Cv)[off] = f2b(v);
                else if constexpr (EPI == 1) ((float*)Cv)[off] = v;
                else if constexpr (EPI == 2) ((float*)Cv)[off] += v;
                else                         atomicAdd(&((float*)Cv)[off], v);
            }
        }
    }
}

// ---------------------------------------------------------------------------
// GEMM 256x256, BK=64, 512 thr (8 waves 2Mx4N), 8-phase schedule with
// register-persistent fragments (each half-tile fragment ds_read ONCE per
// K-tile):
//   P0: read A0,B0 ; stage A1(t+1)->nxt ; MFMA A0B0
//   P1: read B1    ; stage B1(t+1)->nxt ; MFMA A0B1
//   P2: read A1    ; stage B0(t+2)->cur ; MFMA A1B1   (B0 region dead @P0)
//   P3: (no reads) ; stage A0(t+2)->cur ; MFMA A1B0   (A0 region dead @P0)
// Counted s_waitcnt vmcnt(4) once per K-tile boundary. XOR chunk swizzle
// with pre-swizzled global source. Epilogue: fused swiglu bf16 (FF1, paired
// interleaved cols) written at ldc (into the combined A-buffer cols 1024+).
// ---------------------------------------------------------------------------
__global__ __launch_bounds__(512, 2)
void gemm256_ff1(const u16* __restrict__ A, const u16* __restrict__ Bt,
                 u16* __restrict__ C, int K, int lda, int ldb, int ldc)
{
    __shared__ __align__(16) u16 As[2][256 * 64];
    __shared__ __align__(16) u16 Bs[2][256 * 64];
    const int tid  = threadIdx.x;
    const int wave = tid >> 6, lane = tid & 63;
    const int wm = wave >> 2, wn = wave & 3;
    const int frow = lane & 15, fk = lane >> 4;
    const int tn = blockIdx.x * 256;
    const int tm = blockIdx.y * 256;
    const int nt = K >> 6;

    const int lrow  = lane >> 3;
    const int csrc8 = ((lane & 7) ^ lrow) * 8;
    int rbA0[2], rbA1[2], rbB0[2], rbB1[2];
#pragma unroll
    for (int g = 0; g < 2; ++g) {
        const int c = g * 8 + wave;
        const int a0 = ((c >> 3) * 128) + ((c & 7) * 8);
        rbA0[g] = a0; rbA1[g] = a0 + 64;
        const int b0 = ((c >> 2) * 64) + ((c & 3) * 8);
        rbB0[g] = b0; rbB1[g] = b0 + 32;
    }

#define STG(LDS, buf, src, toff, ld, kt, rb)                                                        \
    __builtin_amdgcn_global_load_lds(                                                               \
        (const __attribute__((address_space(1))) void*)((src) + (long)((toff) + (rb) + lrow) * (ld) + ((kt) << 6) + csrc8), \
        (__attribute__((address_space(3))) void*)(&LDS[buf][(rb) * 64]), 16, 0, 0)

#define STAGE_A0(buf, kt) do { STG(As, buf, A,  tm, lda, kt, rbA0[0]); STG(As, buf, A,  tm, lda, kt, rbA0[1]); } while (0)
#define STAGE_A1(buf, kt) do { STG(As, buf, A,  tm, lda, kt, rbA1[0]); STG(As, buf, A,  tm, lda, kt, rbA1[1]); } while (0)
#define STAGE_B0(buf, kt) do { STG(Bs, buf, Bt, tn, ldb, kt, rbB0[0]); STG(Bs, buf, Bt, tn, ldb, kt, rbB0[1]); } while (0)
#define STAGE_B1(buf, kt) do { STG(Bs, buf, Bt, tn, ldb, kt, rbB1[0]); STG(Bs, buf, Bt, tn, ldb, kt, rbB1[1]); } while (0)

#define DSREAD_A(dst, half)                                                                         \
    do { _Pragma("unroll") for (int i = 0; i < 4; ++i) {                                            \
        const int row = wm * 128 + (half) * 64 + i * 16 + frow;                                     \
        _Pragma("unroll") for (int kk = 0; kk < 2; ++kk)                                            \
            dst[i][kk] = *(const bf16x8*)&As[cur][row * 64 + (((kk * 4 + fk) ^ (row & 7)) * 8)];    \
    } } while (0)
#define DSREAD_B(dst, half)                                                                         \
    do { _Pragma("unroll") for (int j = 0; j < 2; ++j) {                                            \
        const int row = wn * 64 + (half) * 32 + j * 16 + frow;                                      \
        _Pragma("unroll") for (int kk = 0; kk < 2; ++kk)                                            \
            dst[j][kk] = *(const bf16x8*)&Bs[cur][row * 64 + (((kk * 4 + fk) ^ (row & 7)) * 8)];    \
    } } while (0)
#define MFMA_Q(afr, bfr, mh, nh)                                                                    \
    do { __builtin_amdgcn_s_setprio(1);                                                             \
    _Pragma("unroll") for (int kk = 0; kk < 2; ++kk)                                                \
        _Pragma("unroll") for (int i = 0; i < 4; ++i)                                               \
            _Pragma("unroll") for (int j = 0; j < 2; ++j)                                           \
                acc[(mh) * 4 + i][(nh) * 2 + j] = __builtin_amdgcn_mfma_f32_16x16x32_bf16(          \
                    afr[i][kk], bfr[j][kk], acc[(mh) * 4 + i][(nh) * 2 + j], 0, 0, 0);              \
    __builtin_amdgcn_s_setprio(0); } while (0)
#define LGKM0 do { asm volatile("s_waitcnt lgkmcnt(0)" ::: "memory"); __builtin_amdgcn_sched_barrier(0); } while (0)
#define SB    __builtin_amdgcn_sched_barrier(0)
#define BAR   __builtin_amdgcn_s_barrier()

    STAGE_B0(0, 0); STAGE_A0(0, 0); STAGE_A1(0, 0); STAGE_B1(0, 0);
    if (nt > 1) {
        STAGE_B0(1, 1); STAGE_A0(1, 1);
        asm volatile("s_waitcnt vmcnt(4)" ::: "memory");
    } else {
        asm volatile("s_waitcnt vmcnt(0)" ::: "memory");
    }
    SB;
    BAR;

    f32x4 acc[8][4] = {};
    bf16x8 a0f[4][2], a1f[4][2], b0f[2][2], b1f[2][2];

    for (int t = 0; t < nt; ++t) {
        const int cur = t & 1, nxt = cur ^ 1;
        DSREAD_A(a0f, 0); DSREAD_B(b0f, 0);
        if (t + 1 < nt) STAGE_A1(nxt, t + 1);
        BAR; LGKM0;
        MFMA_Q(a0f, b0f, 0, 0);
        SB; BAR;
        DSREAD_B(b1f, 1);
        if (t + 1 < nt) STAGE_B1(nxt, t + 1);
        BAR; LGKM0;
        MFMA_Q(a0f, b1f, 0, 1);
        SB; BAR;
        DSREAD_A(a1f, 1);
        if (t + 2 < nt) STAGE_B0(cur, t + 2);
        BAR; LGKM0;
        MFMA_Q(a1f, b1f, 1, 1);
        SB; BAR;
        if (t + 2 < nt) STAGE_A0(cur, t + 2);
        BAR;
        MFMA_Q(a1f, b0f, 1, 0);
        SB;
        if (t + 1 < nt) {
            if (t + 2 < nt) asm volatile("s_waitcnt vmcnt(4)" ::: "memory");
            else            asm volatile("s_waitcnt vmcnt(0)" ::: "memory");
            SB;
            BAR;
        }
    }
#undef BAR
#undef SB
#undef LGKM0
#undef MFMA_Q
#undef DSREAD_A
#undef DSREAD_B
#undef STAGE_A0
#undef STAGE_A1
#undef STAGE_B0
#undef STAGE_B1
#undef STG

    // fused swiglu: B phys rows nf even = a, nf odd = gate;
    // silu col = (tn>>1) + (wn*2 + nf/2)*16 + frow; written at ldc stride.
#pragma unroll
    for (int mf = 0; mf < 8; ++mf) {
        const int gr = tm + wm * 128 + mf * 16 + fk * 4;
#pragma unroll
        for (int np = 0; np < 4; np += 2) {
            const int scol = (tn >> 1) + (wn * 2 + (np >> 1)) * 16 + frow;
            const f32x4 av = acc[mf][np];
            const f32x4 gv = acc[mf][np + 1];
#pragma unroll
            for (int r = 0; r < 4; ++r) {
                const float g = gv[r];
                const float o = av[r] * g / (1.0f + __expf(-g));
                C[(long)(gr + r) * ldc + scol] = f2b(o);
            }
        }
    }
}

// ---------------------------------------------------------------------------
// Flash attention. Grid (32 qtiles, 16 heads, 2 batches), 256 thr = 4 waves;
// QBLK=64 (16 q/wave), JBLK=64. K/V staged via global_load_lds into double-
// buffered LDS shared by all waves. Mask = f32 bias. 40KB LDS -> 4 blocks/CU.
// Output written into combined buffer cols 0..1023 with row stride ldo.
// ---------------------------------------------------------------------------
__global__ __launch_bounds__(256, 4)
void flash_attn(const u16* __restrict__ qb, const u16* __restrict__ kext,
                const u16* __restrict__ vT, const float* __restrict__ mbias,
                u16* __restrict__ aout, int ldo)
{
    __shared__ __align__(16) u16 Ksm[2][4096];   // [64 j][64 d], chunk-swizzled
    __shared__ __align__(16) u16 Vsm[2][4096];   // [64 d][64 j], chunk-swizzled
    __shared__ __align__(16) u16 Psm[4][1024];   // per-wave [16 q][64 j], swz
    const int tid  = threadIdx.x;
    const int wave = tid >> 6, lane = tid & 63;
    const int frow = lane & 15, fk = lane >> 4;
    const int b = blockIdx.z, h = blockIdx.y;
    const int q0 = blockIdx.x * 64;

    const u16* kx = kext + (long)b * 2048 * 64;
    const u16* vb = vT   + (long)b * 64 * 2048;
    const float* mbb = mbias + b * 2048;

    const u16* qbase = qb + ((long)(b * 2048 + q0 + wave * 16 + frow)) * 1024 + h * 64;
    bf16x8 bq[2];
#pragma unroll
    for (int kk = 0; kk < 2; ++kk)
        bq[kk] = *(const bf16x8*)&qbase[kk * 32 + fk * 8];

#define FSTAGE(buf, j0s)                                                                             \
    do {                                                                                             \
        _Pragma("unroll")                                                                            \
        for (int i = 0; i < 2; ++i) {                                                                \
            const int slot = i * 256 + tid;                                                          \
            const int row  = slot >> 3;                                                              \
            const int csrc = (slot & 7) ^ (row & 7);                                                 \
            __builtin_amdgcn_global_load_lds(                                                        \
                (const __attribute__((address_space(1))) void*)(kx + (long)((j0s) + row) * 64 + csrc * 8), \
                (__attribute__((address_space(3))) void*)(&Ksm[buf][(i * 256 + wave * 64) * 8]), 16, 0, 0); \
            __builtin_amdgcn_global_load_lds(                                                        \
                (const __attribute__((address_space(1))) void*)(vb + (long)row * 2048 + (j0s) + csrc * 8),  \
                (__attribute__((address_space(3))) void*)(&Vsm[buf][(i * 256 + wave * 64) * 8]), 16, 0, 0); \
        }                                                                                            \
    } while (0)

    FSTAGE(0, 0);

    f32x4 oacc[4] = {};
    float mrun = -1e30f, lrun = 0.0f;
    u16* pw = &Psm[wave][0];

    for (int it = 0; it < 32; ++it) {
        const int j0 = it * 64;
        __syncthreads();
        float4 mb[4];
#pragma unroll
        for (int m = 0; m < 4; ++m)
            mb[m] = *(const float4*)&mbb[j0 + m * 16 + fk * 4];
        if (it + 1 < 32) FSTAGE((it + 1) & 1, (it + 1) * 64);
        const int cur = it & 1;

        f32x4 st[4] = {};
        __builtin_amdgcn_s_setprio(1);
#pragma unroll
        for (int kk = 0; kk < 2; ++kk) {
            bf16x8 ka[4];
#pragma unroll
            for (int m = 0; m < 4; ++m) {
                const int row = m * 16 + frow;
                ka[m] = *(const bf16x8*)&Ksm[cur][row * 64 + (((kk * 4 + fk) ^ (row & 7)) * 8)];
            }
#pragma unroll
            for (int m = 0; m < 4; ++m)
                st[m] = __builtin_amdgcn_mfma_f32_16x16x32_bf16(ka[m], bq[kk], st[m], 0, 0, 0);
        }
        __builtin_amdgcn_s_setprio(0);

        float sb[4][4];
#pragma unroll
        for (int m = 0; m < 4; ++m)
#pragma unroll
            for (int r = 0; r < 4; ++r) sb[m][r] = st[m][r] + (&mb[m].x)[r];
        float pm = fmaxf(
            fmaxf(fmaxf(sb[0][0], sb[0][1]), fmaxf(sb[0][2], sb[0][3])),
            fmaxf(fmaxf(sb[1][0], sb[1][1]), fmaxf(sb[1][2], sb[1][3])));
        pm = fmaxf(pm, fmaxf(
            fmaxf(fmaxf(sb[2][0], sb[2][1]), fmaxf(sb[2][2], sb[2][3])),
            fmaxf(fmaxf(sb[3][0], sb[3][1]), fmaxf(sb[3][2], sb[3][3]))));
        pm = fmaxf(pm, __shfl_xor(pm, 16));
        pm = fmaxf(pm, __shfl_xor(pm, 32));
        const float nm = fmaxf(mrun, pm);
        const float alpha = __expf(mrun - nm);
        mrun = nm;

        float rs = 0.0f;
#pragma unroll
        for (int m = 0; m < 4; ++m) {
            const float p0 = __expf(sb[m][0] - nm);
            const float p1 = __expf(sb[m][1] - nm);
            const float p2 = __expf(sb[m][2] - nm);
            const float p3 = __expf(sb[m][3] - nm);
            rs += (p0 + p1) + (p2 + p3);
            const int chunk = (m * 2 + (fk >> 1)) ^ (frow & 7);
            uint2 w; w.x = pack2(p0, p1); w.y = pack2(p2, p3);
            *(uint2*)&pw[frow * 64 + chunk * 8 + (fk & 1) * 4] = w;
        }
        rs += __shfl_xor(rs, 16);
        rs += __shfl_xor(rs, 32);
        lrun = lrun * alpha + rs;
#pragma unroll
        for (int mo = 0; mo < 4; ++mo)
#pragma unroll
            for (int r = 0; r < 4; ++r) oacc[mo][r] *= alpha;

        __builtin_amdgcn_s_setprio(1);
#pragma unroll
        for (int kkv = 0; kkv < 2; ++kkv) {
            bf16x8 va[4];
#pragma unroll
            for (int mo = 0; mo < 4; ++mo) {
                const int row = mo * 16 + frow;
                va[mo] = *(const bf16x8*)&Vsm[cur][row * 64 + (((kkv * 4 + fk) ^ (row & 7)) * 8)];
            }
            const bf16x8 pb = *(const bf16x8*)&pw[frow * 64 + (((kkv * 4 + fk) ^ (frow & 7)) * 8)];
#pragma unroll
            for (int mo = 0; mo < 4; ++mo)
                oacc[mo] = __builtin_amdgcn_mfma_f32_16x16x32_bf16(va[mo], pb, oacc[mo], 0, 0, 0);
        }
        __builtin_amdgcn_s_setprio(0);
    }
#undef FSTAGE

    const float inv = 1.0f / lrun;
    const long row = (long)b * 2048 + q0 + wave * 16 + frow;
#pragma unroll
    for (int mo = 0; mo < 4; ++mo) {
        uint2 w;
        w.x = pack2(oacc[mo][0] * inv, oacc[mo][1] * inv);
        w.y = pack2(oacc[mo][2] * inv, oacc[mo][3] * inv);
        *(uint2*)&aout[row * ldo + h * 64 + mo * 16 + fk * 4] = w;
    }
}

// ---------------------------------------------------------------------------
extern "C" void kernel_launch(void* const* d_in, const int* in_sizes, int n_in,
                              void* d_out, int out_size, void* d_ws, size_t ws_size,
                              hipStream_t stream)
{
    const float* x      = (const float*)d_in[0];
    const float* ctx    = (const float*)d_in[1];
    const int*   mask   = (const int*)d_in[2];
    const float* gamma  = (const float*)d_in[3];
    const float* cgamma = (const float*)d_in[4];
    const float* Wq     = (const float*)d_in[5];
    const float* Wkv    = (const float*)d_in[6];
    const float* Wout   = (const float*)d_in[7];
    const float* Wff1   = (const float*)d_in[8];
    const float* Wff2   = (const float*)d_in[9];
    float* out = (float*)d_out;

    char* w = (char*)d_ws;
    auto carveB = [&](long bytes) { char* p = w; w += ((bytes + 255) / 256) * 256; return p; };
    u16*   xn     = (u16*)  carveB(4096L * 1024 * 2);
    u16*   ctxn   = (u16*)  carveB(4096L * 1024 * 2);
    u16*   WqT    = (u16*)  carveB(1024L * 1024 * 2);
    u16*   WkvT   = (u16*)  carveB(128L * 1024 * 2);
    u16*   bigW   = (u16*)  carveB(1024L * 5120 * 2);   // [n=1024][k=5120]: Wout^T | Wff2^T
    u16*   Wff1Tp = (u16*)  carveB(8192L * 1024 * 2);
    u16*   q      = (u16*)  carveB(4096L * 1024 * 2);
    float* kvf    = (float*)carveB(2L * 2048 * 128 * 4);
    u16*   kext   = (u16*)  carveB(2L * 2048 * 64 * 2);
    float* mbias  = (float*)carveB(2L * 2048 * 4);
    u16*   vT     = (u16*)  carveB(2L * 64 * 2048 * 2);
    u16*   comb   = (u16*)  carveB(4096L * 5120 * 2);   // [m=4096][k=5120]: aout | gbuf

    dim3 B(256);

    ln_kernel<<<dim3(8192), B, 0, stream>>>(x, ctx, gamma, cgamma, xn, ctxn);
    wconv<<<dim3(32, 32),  B, 0, stream>>>(Wq,   WqT,  1024, 1024, 1024, 0,    0.125f);  // q scale folded
    wconv<<<dim3(4, 32),   B, 0, stream>>>(Wkv,  WkvT, 128,  1024, 1024, 0,    1.0f);
    wconv<<<dim3(32, 32),  B, 0, stream>>>(Wout, bigW, 1024, 1024, 5120, 0,    1.0f);
    wconv<<<dim3(32, 128), B, 0, stream>>>(Wff2, bigW, 1024, 4096, 5120, 1024, 1.0f);
    wconv_ff1<<<dim3(256, 32), B, 0, stream>>>(Wff1, Wff1Tp);

    // q = xn @ WqT^T : M=4096 N=1024 K=1024
    gemm_bt<0><<<dim3(8, 32, 1), B, 0, stream>>>(xn, WqT, q, 1024, 1024, 1024, 1024, 0, 0, 0);
    // kvf = ctxn @ WkvT^T (f32, split-K x4 atomic): M=4096 N=128 K=1024
    hipMemsetAsync(kvf, 0, 2L * 2048 * 128 * 4, stream);
    gemm_bt<4><<<dim3(1, 32, 4), B, 0, stream>>>(ctxn, WkvT, kvf, 256, 1024, 1024, 128, 256, 256, 0);
    kext_build<<<dim3(128), B, 0, stream>>>(kvf, mask, kext, mbias);
    vtrans<<<dim3(8, 64, 2), B, 0, stream>>>(kvf, vT);

    // fused attention -> comb cols 0..1023 (row stride 5120)
    flash_attn<<<dim3(32, 16, 2), B, 0, stream>>>(q, kext, vT, mbias, comb, 5120);

    // comb cols 1024..5119 = swiglu(xn @ Wff1Tp^T) : 8-phase 256^2 GEMM
    gemm256_ff1<<<dim3(32, 16), dim3(512), 0, stream>>>(xn, Wff1Tp, comb + 1024, 1024, 1024, 1024, 5120);

    // out = comb @ bigW^T : M=4096 N=1024 K=5120 (single fused output GEMM)
    gemm_bt<1><<<dim3(8, 32, 1), B, 0, stream>>>(comb, bigW, out, 5120, 5120, 5120, 1024, 0, 0, 0);
}